// Round 5
// baseline (541.449 us; speedup 1.0000x reference)
//
#include <hip/hip_runtime.h>
#include <hip/hip_bf16.h>
#include <stdint.h>

typedef __attribute__((ext_vector_type(8))) short short8;
typedef __attribute__((ext_vector_type(4))) float floatx4;

#define NB 4
#define NN 8192
#define NC 768
#define NH 12
#define ND 64
#define LDQKV 2304
#define NSPLIT 16

// ---------- helpers ----------
__device__ __forceinline__ float bf2f(ushort u) {
    union { float f; uint32_t i; } x; x.i = ((uint32_t)u) << 16; return x.f;
}
__device__ __forceinline__ ushort f2bf(float f) {
    union { float f; uint32_t i; } x; x.f = f;
    uint32_t r = x.i + 0x7fff + ((x.i >> 16) & 1);
    return (ushort)(r >> 16);
}
typedef const __attribute__((address_space(1))) uint32_t* gas1_t;
typedef __attribute__((address_space(3))) uint32_t* las3_t;
__device__ __forceinline__ void gl_lds16(const void* g, const void* l) {
    __builtin_amdgcn_global_load_lds((gas1_t)(uintptr_t)g,
                                     (las3_t)(uint32_t)(uintptr_t)l, 16, 0, 0);
}

// ---------- fp32 -> bf16 bulk convert of X, Wqkv, Wproj in one launch ----------
__global__ __launch_bounds__(256) void cvt_all(const float* __restrict__ X,
                                               const float* __restrict__ Wq,
                                               const float* __restrict__ Wp,
                                               ushort* __restrict__ xbf,
                                               ushort* __restrict__ wqbf,
                                               ushort* __restrict__ wpbf) {
    const int nx = 32768 * 768, nwq = 2304 * 768, nwp = 768 * 768;
    int i = (blockIdx.x * 256 + threadIdx.x) * 8;
    const float* src; ushort* dst;
    if (i < nx)            { src = X + i;              dst = xbf + i; }
    else if (i < nx + nwq) { i -= nx;  src = Wq + i;   dst = wqbf + i; }
    else                   { i -= nx + nwq; if (i >= nwp) return; src = Wp + i; dst = wpbf + i; }
    const float4 a = *(const float4*)src;
    const float4 b = *(const float4*)(src + 4);
    short8 v;
    v[0] = (short)f2bf(a.x); v[1] = (short)f2bf(a.y);
    v[2] = (short)f2bf(a.z); v[3] = (short)f2bf(a.w);
    v[4] = (short)f2bf(b.x); v[5] = (short)f2bf(b.y);
    v[6] = (short)f2bf(b.z); v[7] = (short)f2bf(b.w);
    *(short8*)dst = v;
}

// ---------- GEMM: C[M, n-slice] = act(A[M,K] @ Bw[N,K]^T (+ bias)) ----------
// 128x64 block tile, BK=32, 4 waves (2 m-halves x 2 n-halves), wave tile
// 64x32 = 4x2 of 16x16x32 MFMA -> acc=32 regs, ~85-100 total => 5 waves/SIMD,
// 12 KB LDS => 5 blocks/CU resident (occupancy is the R4-measured limiter).
// LDS chunk (row, kc) lives at slot row*4 + (kc^(row&3)) (XOR swizzle keeps
// gl_lds16 lane->base+16*lane contiguity; frag reads 2-way = free).
template<int LDC, bool ELU, bool BIAS, typename OutT>
__global__ __launch_bounds__(256, 5) void gemm_bt(const ushort* __restrict__ A,
                                                  const ushort* __restrict__ Bw,
                                                  const float* __restrict__ bias,
                                                  OutT* __restrict__ Cout, int K) {
    __shared__ ushort As[128 * 32];   // 8 KB: 8 chunks of 1 KB (16 rows x 64 B)
    __shared__ ushort Bs[64 * 32];    // 4 KB: 4 chunks
    const int t = threadIdx.x;
    const int w = t >> 6, lane = t & 63, l16 = lane & 15, quad = lane >> 4;
    const int wm = w & 1, wn = w >> 1;
    const int m0 = blockIdx.y * 128, n0 = blockIdx.x * 64;

    floatx4 acc[4][2] = {};

    const int rT = lane >> 2;                       // 0..15 rows per 1 KB chunk
    const int c4 = (lane & 3) ^ (rT & 3);           // swizzled k-chunk fetch
    const ushort* gA1 = A  + (size_t)(m0 + 32 * w + rT) * K + c4 * 8;
    const ushort* gA2 = gA1 + (size_t)16 * K;
    const ushort* gB  = Bw + (size_t)(n0 + 16 * w + rT) * K + c4 * 8;

    for (int k0 = 0; k0 < K; k0 += 32) {
        gl_lds16(gA1 + k0, As + 1024 * w);
        gl_lds16(gA2 + k0, As + 1024 * w + 512);
        gl_lds16(gB  + k0, Bs + 512 * w);
        __syncthreads();
        short8 af[4], bfr[2];
        #pragma unroll
        for (int i = 0; i < 4; i++) {
            const int row = wm * 64 + i * 16 + l16;
            af[i] = *(const short8*)&As[(row * 4 + (quad ^ (l16 & 3))) * 8];
        }
        #pragma unroll
        for (int j = 0; j < 2; j++) {
            const int row = wn * 32 + j * 16 + l16;
            bfr[j] = *(const short8*)&Bs[(row * 4 + (quad ^ (l16 & 3))) * 8];
        }
        #pragma unroll
        for (int i = 0; i < 4; i++)
            #pragma unroll
            for (int j = 0; j < 2; j++)
                acc[i][j] = __builtin_amdgcn_mfma_f32_16x16x32_bf16(af[i], bfr[j], acc[i][j], 0, 0, 0);
        __syncthreads();
    }

    #pragma unroll
    for (int i = 0; i < 4; i++) {
        const int row = m0 + wm * 64 + i * 16 + quad * 4;
        #pragma unroll
        for (int j = 0; j < 2; j++) {
            const int col = n0 + wn * 32 + j * 16 + l16;
            float bval = 0.f;
            if (BIAS) bval = bias[col];
            OutT* cp = Cout + (size_t)row * LDC + col;
            #pragma unroll
            for (int r = 0; r < 4; r++) {
                float v = acc[i][j][r];
                if (ELU) { if (col < 2 * NC) v = (v > 0.f) ? v + 1.f : __expf(v); }
                if (BIAS) v += bval;
                if (sizeof(OutT) == 2) *cp = (OutT)f2bf(v);
                else                   *cp = (OutT)v;
                cp += LDC;
            }
        }
    }
}

// ---------- kv/ksum partials: per (slice, bh) block over 512 rows ----------
__global__ __launch_bounds__(256) void kv_ksum(const ushort* __restrict__ qkv,
                                               float* __restrict__ kvpart,
                                               float* __restrict__ kspart) {
    __shared__ ushort klds[128 * 64];
    __shared__ ushort vlds[128 * 64];
    __shared__ float  kvred[64 * 64];
    __shared__ float  ksred[4][64];
    const int bh = blockIdx.y, b = bh / NH, h = bh % NH;
    const int t = threadIdx.x, w = t >> 6, lane = t & 63, l16 = lane & 15, quad = lane >> 4;
    const int n0 = blockIdx.x * 512;
    const ushort* kbase = qkv + (size_t)(b * NN) * LDQKV + NC     + h * ND;
    const ushort* vbase = qkv + (size_t)(b * NN) * LDQKV + 2 * NC + h * ND;

    floatx4 acc[4][4] = {};
    floatx4 acc5[4] = {};
    short8 ones;
    #pragma unroll
    for (int j = 0; j < 8; j++) ones[j] = (l16 == 0) ? (short)0x3F80 : (short)0;

    const int rowT = t >> 3, ch = t & 7;

    for (int s = 0; s < 4; s++) {
        const int nb = n0 + s * 128;
        #pragma unroll
        for (int i = 0; i < 4; i++) {
            const size_t r = (size_t)(nb + i * 32 + rowT) * LDQKV + ch * 8;
            gl_lds16(kbase + r, klds + i * 2048 + w * 512);
            gl_lds16(vbase + r, vlds + i * 2048 + w * 512);
        }
        __syncthreads();
        short8 af[4], bfr[4];
        #pragma unroll
        for (int dt = 0; dt < 4; dt++) {
            short8 v;
            #pragma unroll
            for (int j = 0; j < 8; j++)
                v[j] = (short)klds[(w * 32 + quad * 8 + j) * 64 + dt * 16 + l16];
            af[dt] = v;
        }
        #pragma unroll
        for (int et = 0; et < 4; et++) {
            short8 v;
            #pragma unroll
            for (int j = 0; j < 8; j++)
                v[j] = (short)vlds[(w * 32 + quad * 8 + j) * 64 + et * 16 + l16];
            bfr[et] = v;
        }
        #pragma unroll
        for (int dt = 0; dt < 4; dt++) {
            #pragma unroll
            for (int et = 0; et < 4; et++)
                acc[dt][et] = __builtin_amdgcn_mfma_f32_16x16x32_bf16(af[dt], bfr[et], acc[dt][et], 0, 0, 0);
            acc5[dt] = __builtin_amdgcn_mfma_f32_16x16x32_bf16(af[dt], ones, acc5[dt], 0, 0, 0);
        }
        __syncthreads();
    }

    if (w == 0) {
        #pragma unroll
        for (int dt = 0; dt < 4; dt++)
            #pragma unroll
            for (int et = 0; et < 4; et++)
                #pragma unroll
                for (int r = 0; r < 4; r++)
                    kvred[(dt * 16 + quad * 4 + r) * 64 + et * 16 + l16] = acc[dt][et][r];
    }
    if (l16 == 0) {
        #pragma unroll
        for (int dt = 0; dt < 4; dt++)
            #pragma unroll
            for (int r = 0; r < 4; r++)
                ksred[w][dt * 16 + quad * 4 + r] = acc5[dt][r];
    }
    __syncthreads();
    if (w != 0) {
        #pragma unroll
        for (int dt = 0; dt < 4; dt++)
            #pragma unroll
            for (int et = 0; et < 4; et++)
                #pragma unroll
                for (int r = 0; r < 4; r++)
                    atomicAdd(&kvred[(dt * 16 + quad * 4 + r) * 64 + et * 16 + l16], acc[dt][et][r]);
    }
    __syncthreads();
    float* kvp = kvpart + ((size_t)blockIdx.x * 48 + bh) * 4096;
    for (int i = t; i < 4096; i += 256) kvp[i] = kvred[i];
    if (t < 64) kspart[((size_t)blockIdx.x * 48 + bh) * 64 + t] =
        ksred[0][t] + ksred[1][t] + ksred[2][t] + ksred[3][t];
}

// ---------- reduce partials ----------
__global__ __launch_bounds__(256) void reduce_kvks(const float* __restrict__ kvpart,
                                                   const float* __restrict__ kspart,
                                                   float* __restrict__ kvfinal,
                                                   float* __restrict__ ksfinal) {
    const int bh = blockIdx.y, t = threadIdx.x;
    if (blockIdx.x < 16) {
        const int i = blockIdx.x * 256 + t;
        float s = 0.f;
        #pragma unroll
        for (int p = 0; p < NSPLIT; p++) s += kvpart[((size_t)p * 48 + bh) * 4096 + i];
        kvfinal[(size_t)bh * 4096 + i] = s;
    } else if (t < 64) {
        float s = 0.f;
        #pragma unroll
        for (int p = 0; p < NSPLIT; p++) s += kspart[((size_t)p * 48 + bh) * 64 + t];
        ksfinal[bh * 64 + t] = s;
    }
}

// ---------- out_pre = (q @ kv) / (q . ksum + 1e-6), bf16 ----------
__global__ __launch_bounds__(256) void attn_apply(const ushort* __restrict__ qkv,
                                                  const float* __restrict__ kvfinal,
                                                  const float* __restrict__ ksfinal,
                                                  ushort* __restrict__ outpre) {
    __shared__ ushort kvb[64 * 80];
    const int bh = blockIdx.y, b = bh / NH, h = bh % NH;
    const int t = threadIdx.x, w = t >> 6, lane = t & 63, l16 = lane & 15, quad = lane >> 4;

    for (int i = t; i < 4096; i += 256) {
        const int d = i >> 6, e = i & 63;
        kvb[d * 80 + e] = f2bf(kvfinal[(size_t)bh * 4096 + i]);
    }
    for (int i = t; i < 1024; i += 256) {
        const int d = i >> 4, c = i & 15;
        kvb[d * 80 + 64 + c] = (c == 0) ? f2bf(ksfinal[bh * 64 + d]) : (ushort)0;
    }
    __syncthreads();

    short8 bfr[5][2];
    #pragma unroll
    for (int et = 0; et < 5; et++)
        #pragma unroll
        for (int ks = 0; ks < 2; ks++) {
            short8 v;
            #pragma unroll
            for (int j = 0; j < 8; j++)
                v[j] = (short)kvb[(ks * 32 + quad * 8 + j) * 80 + et * 16 + l16];
            bfr[et][ks] = v;
        }

    const ushort* qbase = qkv + (size_t)(b * NN) * LDQKV + h * ND;
    ushort* obase = outpre + (size_t)(b * NN) * NC + h * ND;
    const int n0 = blockIdx.x * 512;

    for (int it = 0; it < 8; it++) {
        const int nt = n0 + (it * 4 + w) * 16;
        const ushort* qp = qbase + (size_t)(nt + l16) * LDQKV + quad * 8;
        const short8 a0 = *(const short8*)qp;
        const short8 a1 = *(const short8*)(qp + 32);
        floatx4 acc[5] = {};
        #pragma unroll
        for (int et = 0; et < 5; et++) {
            acc[et] = __builtin_amdgcn_mfma_f32_16x16x32_bf16(a0, bfr[et][0], acc[et], 0, 0, 0);
            acc[et] = __builtin_amdgcn_mfma_f32_16x16x32_bf16(a1, bfr[et][1], acc[et], 0, 0, 0);
        }
        float dv[4];
        #pragma unroll
        for (int r = 0; r < 4; r++) dv[r] = __shfl(acc[4][r], lane & 48);
        #pragma unroll
        for (int et = 0; et < 4; et++)
            #pragma unroll
            for (int r = 0; r < 4; r++) {
                const float o = acc[et][r] / (dv[r] + 1e-6f);
                obase[(size_t)(nt + quad * 4 + r) * NC + et * 16 + l16] = f2bf(o);
            }
    }
}

extern "C" void kernel_launch(void* const* d_in, const int* in_sizes, int n_in,
                              void* d_out, int out_size, void* d_ws, size_t ws_size,
                              hipStream_t stream) {
    (void)in_sizes; (void)n_in; (void)out_size; (void)ws_size;
    const float* X     = (const float*)d_in[0];
    const float* Wqkv  = (const float*)d_in[1];
    const float* Wproj = (const float*)d_in[2];
    const float* bproj = (const float*)d_in[3];
    float* out = (float*)d_out;

    char* ws = (char*)d_ws;
    size_t off = 0;
    ushort* qkv     = (ushort*)(ws + off); off += (size_t)32768 * 2304 * 2;
    ushort* outpre  = (ushort*)(ws + off); off += (size_t)32768 * 768 * 2;
    ushort* xbf     = (ushort*)(ws + off); off += (size_t)32768 * 768 * 2;
    ushort* wqkvbf  = (ushort*)(ws + off); off += (size_t)2304 * 768 * 2;
    ushort* wprojbf = (ushort*)(ws + off); off += (size_t)768 * 768 * 2;
    float* kvpart  = (float*)xbf;                             // aliases dead xbf
    float* kspart  = kvpart + (size_t)NSPLIT * 48 * 4096;
    float* kvfinal = kspart + (size_t)NSPLIT * 48 * 64;
    float* ksfinal = kvfinal + (size_t)48 * 4096;

    const int ncvt = (32768 * 768 + 2304 * 768 + 768 * 768) / 8 / 256;
    cvt_all<<<ncvt, 256, 0, stream>>>(X, Wqkv, Wproj, xbf, wqkvbf, wprojbf);

    gemm_bt<LDQKV, true, false, ushort><<<dim3(36, 256), 256, 0, stream>>>(xbf, wqkvbf, nullptr, qkv, NC);
    kv_ksum<<<dim3(NSPLIT, 48), 256, 0, stream>>>(qkv, kvpart, kspart);
    reduce_kvks<<<dim3(17, 48), 256, 0, stream>>>(kvpart, kspart, kvfinal, ksfinal);
    attn_apply<<<dim3(NSPLIT, 48), 256, 0, stream>>>(qkv, kvfinal, ksfinal, outpre);
    gemm_bt<NC, false, true, float><<<dim3(12, 256), 256, 0, stream>>>(outpre, wprojbf, bproj, out, NC);
}

// Round 6
// 507.243 us; speedup vs baseline: 1.0674x; 1.0674x over previous
//
#include <hip/hip_runtime.h>
#include <hip/hip_bf16.h>
#include <stdint.h>

typedef __attribute__((ext_vector_type(8))) short short8;
typedef __attribute__((ext_vector_type(4))) short short4v;
typedef __attribute__((ext_vector_type(4))) float floatx4;
typedef __attribute__((ext_vector_type(16))) float floatx16;

#define NB 4
#define NN 8192
#define NC 768
#define NH 12
#define ND 64
#define MTOT 32768
#define NSPLIT 16

// ---------- helpers ----------
__device__ __forceinline__ float bf2f(ushort u) {
    union { float f; uint32_t i; } x; x.i = ((uint32_t)u) << 16; return x.f;
}
__device__ __forceinline__ ushort f2bf(float f) {
    union { float f; uint32_t i; } x; x.f = f;
    uint32_t r = x.i + 0x7fff + ((x.i >> 16) & 1);
    return (ushort)(r >> 16);
}
typedef const __attribute__((address_space(1))) uint32_t* gas1_t;
typedef __attribute__((address_space(3))) uint32_t* las3_t;
__device__ __forceinline__ void gl_lds16(const void* g, const void* l) {
    __builtin_amdgcn_global_load_lds((gas1_t)(uintptr_t)g,
                                     (las3_t)(uint32_t)(uintptr_t)l, 16, 0, 0);
}

// ---------- fp32 -> bf16 bulk convert ----------
__global__ __launch_bounds__(256) void cvt_all(const float* __restrict__ X,
                                               const float* __restrict__ Wq,
                                               const float* __restrict__ Wp,
                                               ushort* __restrict__ xbf,
                                               ushort* __restrict__ wqbf,
                                               ushort* __restrict__ wpbf) {
    const int nx = MTOT * NC, nwq = 3 * NC * NC, nwp = NC * NC;
    int i = (blockIdx.x * 256 + threadIdx.x) * 8;
    const float* src; ushort* dst;
    if (i < nx)            { src = X + i;              dst = xbf + i; }
    else if (i < nx + nwq) { i -= nx;  src = Wq + i;   dst = wqbf + i; }
    else                   { i -= nx + nwq; if (i >= nwp) return; src = Wp + i; dst = wpbf + i; }
    const float4 a = *(const float4*)src;
    const float4 b = *(const float4*)(src + 4);
    short8 v;
    v[0] = (short)f2bf(a.x); v[1] = (short)f2bf(a.y);
    v[2] = (short)f2bf(a.z); v[3] = (short)f2bf(a.w);
    v[4] = (short)f2bf(b.x); v[5] = (short)f2bf(b.y);
    v[6] = (short)f2bf(b.z); v[7] = (short)f2bf(b.w);
    *(short8*)dst = v;
}

// ---------- QKV GEMM (R4 config + XCD swizzle + split epilogue) ----------
// 128x128 tile, BK=32, 4 waves 2x2, 2x2 of 32x32x16 MFMA per wave.
// 1D grid 4608; strip=(bx&7)+8*((bx>>3)&31) keeps all 18 col-blocks of a
// row-strip on one XCD (mod-8 dispatch) so A is HBM-fetched once.
// Epilogue: cols<768 -> q (elu+1) token-major; 768..1535 -> kT (elu+1)
// feature-major; >=1536 -> vT feature-major. kT/vT stores are ushort4
// (4 consecutive tokens per acc reg-quad).
__global__ __launch_bounds__(256) void gemm_qkv(const ushort* __restrict__ A,
                                                const ushort* __restrict__ Bw,
                                                ushort* __restrict__ qbuf,
                                                ushort* __restrict__ kT,
                                                ushort* __restrict__ vT) {
    const int K = NC;
    __shared__ ushort As[128 * 32];
    __shared__ ushort Bs[128 * 32];
    const int t = threadIdx.x;
    const int w = t >> 6, lane = t & 63, l32 = lane & 31, hi = lane >> 5;
    const int wm = w & 1, wn = w >> 1;
    const int bx = blockIdx.x;
    const int m0 = ((bx & 7) + 8 * ((bx >> 3) & 31)) * 128;
    const int n0 = (bx >> 8) * 128;

    floatx16 acc[2][2] = {};

    const int rowA = t >> 2, chA = (t & 3) ^ (rowA & 3);
    const ushort* gA = A  + (size_t)(m0 + rowA) * K + chA * 8;
    const ushort* gB = Bw + (size_t)(n0 + rowA) * K + chA * 8;

    for (int k0 = 0; k0 < K; k0 += 32) {
        gl_lds16(gA + k0,                  As + w * 512);
        gl_lds16(gA + k0 + 64 * (size_t)K, As + 2048 + w * 512);
        gl_lds16(gB + k0,                  Bs + w * 512);
        gl_lds16(gB + k0 + 64 * (size_t)K, Bs + 2048 + w * 512);
        __syncthreads();
        short8 af[2][2], bfr[2][2];
        #pragma unroll
        for (int mt = 0; mt < 2; mt++)
            #pragma unroll
            for (int kh = 0; kh < 2; kh++) {
                const int row = wm * 64 + mt * 32 + l32;
                const int kc = kh * 2 + hi;
                af[mt][kh] = *(const short8*)&As[(row * 4 + (kc ^ (row & 3))) * 8];
            }
        #pragma unroll
        for (int nt = 0; nt < 2; nt++)
            #pragma unroll
            for (int kh = 0; kh < 2; kh++) {
                const int row = wn * 64 + nt * 32 + l32;
                const int kc = kh * 2 + hi;
                bfr[nt][kh] = *(const short8*)&Bs[(row * 4 + (kc ^ (row & 3))) * 8];
            }
        #pragma unroll
        for (int mt = 0; mt < 2; mt++)
            #pragma unroll
            for (int nt = 0; nt < 2; nt++)
                #pragma unroll
                for (int kh = 0; kh < 2; kh++)
                    acc[mt][nt] = __builtin_amdgcn_mfma_f32_32x32x16_bf16(
                        af[mt][kh], bfr[nt][kh], acc[mt][nt], 0, 0, 0);
        __syncthreads();
    }

    #pragma unroll
    for (int mt = 0; mt < 2; mt++)
        #pragma unroll
        for (int nt = 0; nt < 2; nt++) {
            const int col = n0 + wn * 64 + nt * 32 + l32;
            const int rbase = m0 + wm * 64 + mt * 32 + 4 * hi;
            if (col < NC) {                      // q: token-major, elu+1
                #pragma unroll
                for (int reg = 0; reg < 16; reg++) {
                    const int row = rbase + (reg & 3) + 8 * (reg >> 2);
                    float v = acc[mt][nt][reg];
                    v = (v > 0.f) ? v + 1.f : __expf(v);
                    qbuf[(size_t)row * NC + col] = f2bf(v);
                }
            } else {
                const bool isK = col < 2 * NC;
                ushort* dst = isK ? (kT + (size_t)(col - NC) * MTOT)
                                  : (vT + (size_t)(col - 2 * NC) * MTOT);
                #pragma unroll
                for (int rq = 0; rq < 4; rq++) {
                    short4v pk;
                    #pragma unroll
                    for (int r = 0; r < 4; r++) {
                        float v = acc[mt][nt][rq * 4 + r];
                        if (isK) v = (v > 0.f) ? v + 1.f : __expf(v);
                        pk[r] = (short)f2bf(v);
                    }
                    *(short4v*)&dst[rbase + 8 * rq] = pk;
                }
            }
        }
}

// ---------- Proj GEMM (R4 config + XCD swizzle), fp32 out + bias ----------
__global__ __launch_bounds__(256) void gemm_proj(const ushort* __restrict__ A,
                                                 const ushort* __restrict__ Bw,
                                                 const float* __restrict__ bias,
                                                 float* __restrict__ Cout) {
    const int K = NC;
    __shared__ ushort As[128 * 32];
    __shared__ ushort Bs[128 * 32];
    const int t = threadIdx.x;
    const int w = t >> 6, lane = t & 63, l32 = lane & 31, hi = lane >> 5;
    const int wm = w & 1, wn = w >> 1;
    const int bx = blockIdx.x;
    const int m0 = ((bx & 7) + 8 * ((bx >> 3) & 31)) * 128;
    const int n0 = (bx >> 8) * 128;

    floatx16 acc[2][2] = {};

    const int rowA = t >> 2, chA = (t & 3) ^ (rowA & 3);
    const ushort* gA = A  + (size_t)(m0 + rowA) * K + chA * 8;
    const ushort* gB = Bw + (size_t)(n0 + rowA) * K + chA * 8;

    for (int k0 = 0; k0 < K; k0 += 32) {
        gl_lds16(gA + k0,                  As + w * 512);
        gl_lds16(gA + k0 + 64 * (size_t)K, As + 2048 + w * 512);
        gl_lds16(gB + k0,                  Bs + w * 512);
        gl_lds16(gB + k0 + 64 * (size_t)K, Bs + 2048 + w * 512);
        __syncthreads();
        short8 af[2][2], bfr[2][2];
        #pragma unroll
        for (int mt = 0; mt < 2; mt++)
            #pragma unroll
            for (int kh = 0; kh < 2; kh++) {
                const int row = wm * 64 + mt * 32 + l32;
                const int kc = kh * 2 + hi;
                af[mt][kh] = *(const short8*)&As[(row * 4 + (kc ^ (row & 3))) * 8];
            }
        #pragma unroll
        for (int nt = 0; nt < 2; nt++)
            #pragma unroll
            for (int kh = 0; kh < 2; kh++) {
                const int row = wn * 64 + nt * 32 + l32;
                const int kc = kh * 2 + hi;
                bfr[nt][kh] = *(const short8*)&Bs[(row * 4 + (kc ^ (row & 3))) * 8];
            }
        #pragma unroll
        for (int mt = 0; mt < 2; mt++)
            #pragma unroll
            for (int nt = 0; nt < 2; nt++)
                #pragma unroll
                for (int kh = 0; kh < 2; kh++)
                    acc[mt][nt] = __builtin_amdgcn_mfma_f32_32x32x16_bf16(
                        af[mt][kh], bfr[nt][kh], acc[mt][nt], 0, 0, 0);
        __syncthreads();
    }

    #pragma unroll
    for (int mt = 0; mt < 2; mt++)
        #pragma unroll
        for (int nt = 0; nt < 2; nt++) {
            const int col = n0 + wn * 64 + nt * 32 + l32;
            const float bval = bias[col];
            const int rbase = m0 + wm * 64 + mt * 32 + 4 * hi;
            #pragma unroll
            for (int reg = 0; reg < 16; reg++) {
                const int row = rbase + (reg & 3) + 8 * (reg >> 2);
                Cout[(size_t)row * NC + col] = acc[mt][nt][reg] + bval;
            }
        }
}

// ---------- kv/ksum partials from kT/vT (feature-major) ----------
// Per (split, bh): 512 tokens as 4 tiles of 128. LDS tile [feature][token]
// with XOR-swizzled 16B chunks -> vector ds_read_b128 frags, conflict-free.
__global__ __launch_bounds__(256) void kv_ksum(const ushort* __restrict__ kT,
                                               const ushort* __restrict__ vT,
                                               float* __restrict__ kvpart,
                                               float* __restrict__ kspart) {
    __shared__ ushort klds[64 * 128];
    __shared__ ushort vlds[64 * 128];
    __shared__ float  kvred[64 * 64];
    __shared__ float  ksred[4][64];
    const int bh = blockIdx.y, b = bh / NH, h = bh % NH;
    const int t = threadIdx.x, w = t >> 6, lane = t & 63, l16 = lane & 15, quad = lane >> 4;
    const int T0 = b * NN + blockIdx.x * 512;
    const ushort* kTb = kT + (size_t)(h * ND) * MTOT + T0;
    const ushort* vTb = vT + (size_t)(h * ND) * MTOT + T0;

    floatx4 acc[4][4] = {};
    floatx4 acc5[4] = {};
    short8 ones;
    #pragma unroll
    for (int j = 0; j < 8; j++) ones[j] = (l16 == 0) ? (short)0x3F80 : (short)0;

    const int rI = lane >> 4;          // row-within-issue 0..3
    const int sI = lane & 15;          // 16B slot within row

    for (int tl = 0; tl < 4; tl++) {
        #pragma unroll
        for (int i = 0; i < 4; i++) {
            const int r = i * 16 + w * 4 + rI;              // local feature row 0..63
            const int cg = sI ^ (r & 7);                    // swizzled global chunk
            const size_t ga = (size_t)r * MTOT + tl * 128 + cg * 8;
            gl_lds16(kTb + ga, klds + (i * 16 + w * 4) * 128);
            gl_lds16(vTb + ga, vlds + (i * 16 + w * 4) * 128);
        }
        __syncthreads();
        short8 af[4], bfr[4];
        #pragma unroll
        for (int dt = 0; dt < 4; dt++) {
            const int r = dt * 16 + l16;
            const int slot = (w * 4 + quad) ^ (r & 7);
            af[dt] = *(const short8*)&klds[r * 128 + slot * 8];
        }
        #pragma unroll
        for (int et = 0; et < 4; et++) {
            const int r = et * 16 + l16;
            const int slot = (w * 4 + quad) ^ (r & 7);
            bfr[et] = *(const short8*)&vlds[r * 128 + slot * 8];
        }
        #pragma unroll
        for (int dt = 0; dt < 4; dt++) {
            #pragma unroll
            for (int et = 0; et < 4; et++)
                acc[dt][et] = __builtin_amdgcn_mfma_f32_16x16x32_bf16(af[dt], bfr[et], acc[dt][et], 0, 0, 0);
            acc5[dt] = __builtin_amdgcn_mfma_f32_16x16x32_bf16(af[dt], ones, acc5[dt], 0, 0, 0);
        }
        __syncthreads();
    }

    if (w == 0) {
        #pragma unroll
        for (int dt = 0; dt < 4; dt++)
            #pragma unroll
            for (int et = 0; et < 4; et++)
                #pragma unroll
                for (int r = 0; r < 4; r++)
                    kvred[(dt * 16 + quad * 4 + r) * 64 + et * 16 + l16] = acc[dt][et][r];
    }
    if (l16 == 0) {
        #pragma unroll
        for (int dt = 0; dt < 4; dt++)
            #pragma unroll
            for (int r = 0; r < 4; r++)
                ksred[w][dt * 16 + quad * 4 + r] = acc5[dt][r];
    }
    __syncthreads();
    if (w != 0) {
        #pragma unroll
        for (int dt = 0; dt < 4; dt++)
            #pragma unroll
            for (int et = 0; et < 4; et++)
                #pragma unroll
                for (int r = 0; r < 4; r++)
                    atomicAdd(&kvred[(dt * 16 + quad * 4 + r) * 64 + et * 16 + l16], acc[dt][et][r]);
    }
    __syncthreads();
    float* kvp = kvpart + ((size_t)blockIdx.x * 48 + bh) * 4096;
    for (int i = t; i < 4096; i += 256) kvp[i] = kvred[i];
    if (t < 64) kspart[((size_t)blockIdx.x * 48 + bh) * 64 + t] =
        ksred[0][t] + ksred[1][t] + ksred[2][t] + ksred[3][t];
}

// ---------- reduce partials ----------
__global__ __launch_bounds__(256) void reduce_kvks(const float* __restrict__ kvpart,
                                                   const float* __restrict__ kspart,
                                                   float* __restrict__ kvfinal,
                                                   float* __restrict__ ksfinal) {
    const int bh = blockIdx.y, t = threadIdx.x;
    if (blockIdx.x < 16) {
        const int i = blockIdx.x * 256 + t;
        float s = 0.f;
        #pragma unroll
        for (int p = 0; p < NSPLIT; p++) s += kvpart[((size_t)p * 48 + bh) * 4096 + i];
        kvfinal[(size_t)bh * 4096 + i] = s;
    } else if (t < 64) {
        float s = 0.f;
        #pragma unroll
        for (int p = 0; p < NSPLIT; p++) s += kspart[((size_t)p * 48 + bh) * 64 + t];
        ksfinal[bh * 64 + t] = s;
    }
}

// ---------- out_pre = (q @ kv) / (q . ksum + 1e-6), bf16 ----------
__global__ __launch_bounds__(256) void attn_apply(const ushort* __restrict__ qbuf,
                                                  const float* __restrict__ kvfinal,
                                                  const float* __restrict__ ksfinal,
                                                  ushort* __restrict__ outpre) {
    __shared__ ushort kvb[64 * 80];
    const int bh = blockIdx.y, b = bh / NH, h = bh % NH;
    const int t = threadIdx.x, w = t >> 6, lane = t & 63, l16 = lane & 15, quad = lane >> 4;

    for (int i = t; i < 4096; i += 256) {
        const int d = i >> 6, e = i & 63;
        kvb[d * 80 + e] = f2bf(kvfinal[(size_t)bh * 4096 + i]);
    }
    for (int i = t; i < 1024; i += 256) {
        const int d = i >> 4, c = i & 15;
        kvb[d * 80 + 64 + c] = (c == 0) ? f2bf(ksfinal[bh * 64 + d]) : (ushort)0;
    }
    __syncthreads();

    short8 bfr[5][2];
    #pragma unroll
    for (int et = 0; et < 5; et++)
        #pragma unroll
        for (int ks = 0; ks < 2; ks++) {
            short8 v;
            #pragma unroll
            for (int j = 0; j < 8; j++)
                v[j] = (short)kvb[(ks * 32 + quad * 8 + j) * 80 + et * 16 + l16];
            bfr[et][ks] = v;
        }

    const ushort* qbase = qbuf + (size_t)(b * NN) * NC + h * ND;
    ushort* obase = outpre + (size_t)(b * NN) * NC + h * ND;
    const int n0 = blockIdx.x * 512;

    for (int it = 0; it < 8; it++) {
        const int nt = n0 + (it * 4 + w) * 16;
        const ushort* qp = qbase + (size_t)(nt + l16) * NC + quad * 8;
        const short8 a0 = *(const short8*)qp;
        const short8 a1 = *(const short8*)(qp + 32);
        floatx4 acc[5] = {};
        #pragma unroll
        for (int et = 0; et < 5; et++) {
            acc[et] = __builtin_amdgcn_mfma_f32_16x16x32_bf16(a0, bfr[et][0], acc[et], 0, 0, 0);
            acc[et] = __builtin_amdgcn_mfma_f32_16x16x32_bf16(a1, bfr[et][1], acc[et], 0, 0, 0);
        }
        float dv[4];
        #pragma unroll
        for (int r = 0; r < 4; r++) dv[r] = __shfl(acc[4][r], lane & 48);
        #pragma unroll
        for (int et = 0; et < 4; et++)
            #pragma unroll
            for (int r = 0; r < 4; r++) {
                const float o = acc[et][r] / (dv[r] + 1e-6f);
                obase[(size_t)(nt + quad * 4 + r) * NC + et * 16 + l16] = f2bf(o);
            }
    }
}

extern "C" void kernel_launch(void* const* d_in, const int* in_sizes, int n_in,
                              void* d_out, int out_size, void* d_ws, size_t ws_size,
                              hipStream_t stream) {
    (void)in_sizes; (void)n_in; (void)out_size; (void)ws_size;
    const float* X     = (const float*)d_in[0];
    const float* Wqkv  = (const float*)d_in[1];
    const float* Wproj = (const float*)d_in[2];
    const float* bproj = (const float*)d_in[3];
    float* out = (float*)d_out;

    char* ws = (char*)d_ws;
    size_t off = 0;
    ushort* qbuf    = (ushort*)(ws + off); off += (size_t)MTOT * NC * 2;      // 50.3 MB
    ushort* kT      = (ushort*)(ws + off); off += (size_t)NC * MTOT * 2;      // 50.3 MB
    ushort* vT      = (ushort*)(ws + off); off += (size_t)NC * MTOT * 2;      // 50.3 MB
    ushort* outpre  = (ushort*)(ws + off); off += (size_t)MTOT * NC * 2;      // 50.3 MB
    ushort* xbf     = (ushort*)(ws + off); off += (size_t)MTOT * NC * 2;      // 50.3 MB
    ushort* wqkvbf  = (ushort*)(ws + off); off += (size_t)3 * NC * NC * 2;    //  3.5 MB
    ushort* wprojbf = (ushort*)(ws + off); off += (size_t)NC * NC * 2;        //  1.2 MB
    float* kvpart  = (float*)xbf;                 // aliases xbf (dead after qkv GEMM)
    float* kspart  = kvpart + (size_t)NSPLIT * 48 * 4096;
    float* kvfinal = kspart + (size_t)NSPLIT * 48 * 64;
    float* ksfinal = kvfinal + (size_t)48 * 4096;

    const int ncvt = (MTOT * NC + 3 * NC * NC + NC * NC) / 8 / 256;
    cvt_all<<<ncvt, 256, 0, stream>>>(X, Wqkv, Wproj, xbf, wqkvbf, wprojbf);

    gemm_qkv<<<4608, 256, 0, stream>>>(xbf, wqkvbf, qbuf, kT, vT);
    kv_ksum<<<dim3(NSPLIT, 48), 256, 0, stream>>>(kT, vT, kvpart, kspart);
    reduce_kvks<<<dim3(17, 48), 256, 0, stream>>>(kvpart, kspart, kvfinal, ksfinal);
    attn_apply<<<dim3(NSPLIT, 48), 256, 0, stream>>>(qbuf, kvfinal, ksfinal, outpre);
    gemm_proj<<<1536, 256, 0, stream>>>(outpre, wprojbf, bproj, out);
}

// Round 7
// 502.433 us; speedup vs baseline: 1.0777x; 1.0096x over previous
//
#include <hip/hip_runtime.h>
#include <hip/hip_bf16.h>
#include <stdint.h>

typedef __attribute__((ext_vector_type(8))) short short8;
typedef __attribute__((ext_vector_type(4))) short short4v;
typedef __attribute__((ext_vector_type(4))) float floatx4;
typedef __attribute__((ext_vector_type(16))) float floatx16;

#define NB 4
#define NN 8192
#define NC 768
#define NH 12
#define ND 64
#define MTOT 32768
#define NSPLIT 16

// ---------- helpers ----------
__device__ __forceinline__ float bf2f(ushort u) {
    union { float f; uint32_t i; } x; x.i = ((uint32_t)u) << 16; return x.f;
}
__device__ __forceinline__ ushort f2bf(float f) {
    union { float f; uint32_t i; } x; x.f = f;
    uint32_t r = x.i + 0x7fff + ((x.i >> 16) & 1);
    return (ushort)(r >> 16);
}
typedef const __attribute__((address_space(1))) uint32_t* gas1_t;
typedef __attribute__((address_space(3))) uint32_t* las3_t;
__device__ __forceinline__ void gl_lds16(const void* g, const void* l) {
    __builtin_amdgcn_global_load_lds((gas1_t)(uintptr_t)g,
                                     (las3_t)(uint32_t)(uintptr_t)l, 16, 0, 0);
}

// ---------- fp32 -> bf16 bulk convert ----------
__global__ __launch_bounds__(256) void cvt_all(const float* __restrict__ X,
                                               const float* __restrict__ Wq,
                                               const float* __restrict__ Wp,
                                               ushort* __restrict__ xbf,
                                               ushort* __restrict__ wqbf,
                                               ushort* __restrict__ wpbf) {
    const int nx = MTOT * NC, nwq = 3 * NC * NC, nwp = NC * NC;
    int i = (blockIdx.x * 256 + threadIdx.x) * 8;
    const float* src; ushort* dst;
    if (i < nx)            { src = X + i;              dst = xbf + i; }
    else if (i < nx + nwq) { i -= nx;  src = Wq + i;   dst = wqbf + i; }
    else                   { i -= nx + nwq; if (i >= nwp) return; src = Wp + i; dst = wpbf + i; }
    const float4 a = *(const float4*)src;
    const float4 b = *(const float4*)(src + 4);
    short8 v;
    v[0] = (short)f2bf(a.x); v[1] = (short)f2bf(a.y);
    v[2] = (short)f2bf(a.z); v[3] = (short)f2bf(a.w);
    v[4] = (short)f2bf(b.x); v[5] = (short)f2bf(b.y);
    v[6] = (short)f2bf(b.z); v[7] = (short)f2bf(b.w);
    *(short8*)dst = v;
}

// ---------- QKV GEMM ----------
// 128x128 tile, BK=32, 4 waves 2x2, 2x2 of 32x32x16 MFMA per wave.
// XCD swizzle v2: bx = strip_lo + 8*(colb + 18*strip_hi).
//  - XCD = bx&7 = strip_lo : a strip's 18 col-blocks all land on one XCD.
//  - consecutive work per XCD walks colb FASTEST (R6 had colb slowest ->
//    6.3 MB reuse distance > 4 MB L2; now ~5 live strips x 196 KB + 3.5 MB B ~ L2).
__global__ __launch_bounds__(256) void gemm_qkv(const ushort* __restrict__ A,
                                                const ushort* __restrict__ Bw,
                                                ushort* __restrict__ qbuf,
                                                ushort* __restrict__ kT,
                                                ushort* __restrict__ vT) {
    const int K = NC;
    __shared__ ushort As[128 * 32];
    __shared__ ushort Bs[128 * 32];
    const int t = threadIdx.x;
    const int w = t >> 6, lane = t & 63, l32 = lane & 31, hi = lane >> 5;
    const int wm = w & 1, wn = w >> 1;
    const int bx = blockIdx.x;
    const int rem = bx >> 3;                 // [0,576)
    const int colb = rem % 18, strip = (bx & 7) + 8 * (rem / 18);
    const int m0 = strip * 128, n0 = colb * 128;

    floatx16 acc[2][2] = {};

    const int rowA = t >> 2, chA = (t & 3) ^ (rowA & 3);
    const ushort* gA = A  + (size_t)(m0 + rowA) * K + chA * 8;
    const ushort* gB = Bw + (size_t)(n0 + rowA) * K + chA * 8;

    for (int k0 = 0; k0 < K; k0 += 32) {
        gl_lds16(gA + k0,                  As + w * 512);
        gl_lds16(gA + k0 + 64 * (size_t)K, As + 2048 + w * 512);
        gl_lds16(gB + k0,                  Bs + w * 512);
        gl_lds16(gB + k0 + 64 * (size_t)K, Bs + 2048 + w * 512);
        __syncthreads();
        short8 af[2][2], bfr[2][2];
        #pragma unroll
        for (int mt = 0; mt < 2; mt++)
            #pragma unroll
            for (int kh = 0; kh < 2; kh++) {
                const int row = wm * 64 + mt * 32 + l32;
                const int kc = kh * 2 + hi;
                af[mt][kh] = *(const short8*)&As[(row * 4 + (kc ^ (row & 3))) * 8];
            }
        #pragma unroll
        for (int nt = 0; nt < 2; nt++)
            #pragma unroll
            for (int kh = 0; kh < 2; kh++) {
                const int row = wn * 64 + nt * 32 + l32;
                const int kc = kh * 2 + hi;
                bfr[nt][kh] = *(const short8*)&Bs[(row * 4 + (kc ^ (row & 3))) * 8];
            }
        #pragma unroll
        for (int mt = 0; mt < 2; mt++)
            #pragma unroll
            for (int nt = 0; nt < 2; nt++)
                #pragma unroll
                for (int kh = 0; kh < 2; kh++)
                    acc[mt][nt] = __builtin_amdgcn_mfma_f32_32x32x16_bf16(
                        af[mt][kh], bfr[nt][kh], acc[mt][nt], 0, 0, 0);
        __syncthreads();
    }

    #pragma unroll
    for (int mt = 0; mt < 2; mt++)
        #pragma unroll
        for (int nt = 0; nt < 2; nt++) {
            const int col = n0 + wn * 64 + nt * 32 + l32;
            const int rbase = m0 + wm * 64 + mt * 32 + 4 * hi;
            if (col < NC) {                      // q: token-major, elu+1
                #pragma unroll
                for (int reg = 0; reg < 16; reg++) {
                    const int row = rbase + (reg & 3) + 8 * (reg >> 2);
                    float v = acc[mt][nt][reg];
                    v = (v > 0.f) ? v + 1.f : __expf(v);
                    qbuf[(size_t)row * NC + col] = f2bf(v);
                }
            } else {                             // k,v: feature-major (kT/vT)
                const bool isK = col < 2 * NC;
                ushort* dst = isK ? (kT + (size_t)(col - NC) * MTOT)
                                  : (vT + (size_t)(col - 2 * NC) * MTOT);
                #pragma unroll
                for (int rq = 0; rq < 4; rq++) {
                    short4v pk;
                    #pragma unroll
                    for (int r = 0; r < 4; r++) {
                        float v = acc[mt][nt][rq * 4 + r];
                        if (isK) v = (v > 0.f) ? v + 1.f : __expf(v);
                        pk[r] = (short)f2bf(v);
                    }
                    *(short4v*)&dst[rbase + 8 * rq] = pk;
                }
            }
        }
}

// ---------- Proj GEMM (same swizzle v2, 6 col-blocks), fp32 out + bias ----------
__global__ __launch_bounds__(256) void gemm_proj(const ushort* __restrict__ A,
                                                 const ushort* __restrict__ Bw,
                                                 const float* __restrict__ bias,
                                                 float* __restrict__ Cout) {
    const int K = NC;
    __shared__ ushort As[128 * 32];
    __shared__ ushort Bs[128 * 32];
    const int t = threadIdx.x;
    const int w = t >> 6, lane = t & 63, l32 = lane & 31, hi = lane >> 5;
    const int wm = w & 1, wn = w >> 1;
    const int bx = blockIdx.x;
    const int rem = bx >> 3;                 // [0,192)
    const int colb = rem % 6, strip = (bx & 7) + 8 * (rem / 6);
    const int m0 = strip * 128, n0 = colb * 128;

    floatx16 acc[2][2] = {};

    const int rowA = t >> 2, chA = (t & 3) ^ (rowA & 3);
    const ushort* gA = A  + (size_t)(m0 + rowA) * K + chA * 8;
    const ushort* gB = Bw + (size_t)(n0 + rowA) * K + chA * 8;

    for (int k0 = 0; k0 < K; k0 += 32) {
        gl_lds16(gA + k0,                  As + w * 512);
        gl_lds16(gA + k0 + 64 * (size_t)K, As + 2048 + w * 512);
        gl_lds16(gB + k0,                  Bs + w * 512);
        gl_lds16(gB + k0 + 64 * (size_t)K, Bs + 2048 + w * 512);
        __syncthreads();
        short8 af[2][2], bfr[2][2];
        #pragma unroll
        for (int mt = 0; mt < 2; mt++)
            #pragma unroll
            for (int kh = 0; kh < 2; kh++) {
                const int row = wm * 64 + mt * 32 + l32;
                const int kc = kh * 2 + hi;
                af[mt][kh] = *(const short8*)&As[(row * 4 + (kc ^ (row & 3))) * 8];
            }
        #pragma unroll
        for (int nt = 0; nt < 2; nt++)
            #pragma unroll
            for (int kh = 0; kh < 2; kh++) {
                const int row = wn * 64 + nt * 32 + l32;
                const int kc = kh * 2 + hi;
                bfr[nt][kh] = *(const short8*)&Bs[(row * 4 + (kc ^ (row & 3))) * 8];
            }
        #pragma unroll
        for (int mt = 0; mt < 2; mt++)
            #pragma unroll
            for (int nt = 0; nt < 2; nt++)
                #pragma unroll
                for (int kh = 0; kh < 2; kh++)
                    acc[mt][nt] = __builtin_amdgcn_mfma_f32_32x32x16_bf16(
                        af[mt][kh], bfr[nt][kh], acc[mt][nt], 0, 0, 0);
        __syncthreads();
    }

    #pragma unroll
    for (int mt = 0; mt < 2; mt++)
        #pragma unroll
        for (int nt = 0; nt < 2; nt++) {
            const int col = n0 + wn * 64 + nt * 32 + l32;
            const float bval = bias[col];
            const int rbase = m0 + wm * 64 + mt * 32 + 4 * hi;
            #pragma unroll
            for (int reg = 0; reg < 16; reg++) {
                const int row = rbase + (reg & 3) + 8 * (reg >> 2);
                Cout[(size_t)row * NC + col] = acc[mt][nt][reg] + bval;
            }
        }
}

// ---------- kv/ksum partials from kT/vT (feature-major) ----------
__global__ __launch_bounds__(256) void kv_ksum(const ushort* __restrict__ kT,
                                               const ushort* __restrict__ vT,
                                               float* __restrict__ kvpart,
                                               float* __restrict__ kspart) {
    __shared__ ushort klds[64 * 128];
    __shared__ ushort vlds[64 * 128];
    __shared__ float  kvred[64 * 64];
    __shared__ float  ksred[4][64];
    const int bh = blockIdx.y, b = bh / NH, h = bh % NH;
    const int t = threadIdx.x, w = t >> 6, lane = t & 63, l16 = lane & 15, quad = lane >> 4;
    const int T0 = b * NN + blockIdx.x * 512;
    const ushort* kTb = kT + (size_t)(h * ND) * MTOT + T0;
    const ushort* vTb = vT + (size_t)(h * ND) * MTOT + T0;

    floatx4 acc[4][4] = {};
    floatx4 acc5[4] = {};
    short8 ones;
    #pragma unroll
    for (int j = 0; j < 8; j++) ones[j] = (l16 == 0) ? (short)0x3F80 : (short)0;

    const int rI = lane >> 4;
    const int sI = lane & 15;

    for (int tl = 0; tl < 4; tl++) {
        #pragma unroll
        for (int i = 0; i < 4; i++) {
            const int r = i * 16 + w * 4 + rI;
            const int cg = sI ^ (r & 7);
            const size_t ga = (size_t)r * MTOT + tl * 128 + cg * 8;
            gl_lds16(kTb + ga, klds + (i * 16 + w * 4) * 128);
            gl_lds16(vTb + ga, vlds + (i * 16 + w * 4) * 128);
        }
        __syncthreads();
        short8 af[4], bfr[4];
        #pragma unroll
        for (int dt = 0; dt < 4; dt++) {
            const int r = dt * 16 + l16;
            const int slot = (w * 4 + quad) ^ (r & 7);
            af[dt] = *(const short8*)&klds[r * 128 + slot * 8];
        }
        #pragma unroll
        for (int et = 0; et < 4; et++) {
            const int r = et * 16 + l16;
            const int slot = (w * 4 + quad) ^ (r & 7);
            bfr[et] = *(const short8*)&vlds[r * 128 + slot * 8];
        }
        #pragma unroll
        for (int dt = 0; dt < 4; dt++) {
            #pragma unroll
            for (int et = 0; et < 4; et++)
                acc[dt][et] = __builtin_amdgcn_mfma_f32_16x16x32_bf16(af[dt], bfr[et], acc[dt][et], 0, 0, 0);
            acc5[dt] = __builtin_amdgcn_mfma_f32_16x16x32_bf16(af[dt], ones, acc5[dt], 0, 0, 0);
        }
        __syncthreads();
    }

    if (w == 0) {
        #pragma unroll
        for (int dt = 0; dt < 4; dt++)
            #pragma unroll
            for (int et = 0; et < 4; et++)
                #pragma unroll
                for (int r = 0; r < 4; r++)
                    kvred[(dt * 16 + quad * 4 + r) * 64 + et * 16 + l16] = acc[dt][et][r];
    }
    if (l16 == 0) {
        #pragma unroll
        for (int dt = 0; dt < 4; dt++)
            #pragma unroll
            for (int r = 0; r < 4; r++)
                ksred[w][dt * 16 + quad * 4 + r] = acc5[dt][r];
    }
    __syncthreads();
    if (w != 0) {
        #pragma unroll
        for (int dt = 0; dt < 4; dt++)
            #pragma unroll
            for (int et = 0; et < 4; et++)
                #pragma unroll
                for (int r = 0; r < 4; r++)
                    atomicAdd(&kvred[(dt * 16 + quad * 4 + r) * 64 + et * 16 + l16], acc[dt][et][r]);
    }
    __syncthreads();
    float* kvp = kvpart + ((size_t)blockIdx.x * 48 + bh) * 4096;
    for (int i = t; i < 4096; i += 256) kvp[i] = kvred[i];
    if (t < 64) kspart[((size_t)blockIdx.x * 48 + bh) * 64 + t] =
        ksred[0][t] + ksred[1][t] + ksred[2][t] + ksred[3][t];
}

// ---------- reduce partials ----------
__global__ __launch_bounds__(256) void reduce_kvks(const float* __restrict__ kvpart,
                                                   const float* __restrict__ kspart,
                                                   float* __restrict__ kvfinal,
                                                   float* __restrict__ ksfinal) {
    const int bh = blockIdx.y, t = threadIdx.x;
    if (blockIdx.x < 16) {
        const int i = blockIdx.x * 256 + t;
        float s = 0.f;
        #pragma unroll
        for (int p = 0; p < NSPLIT; p++) s += kvpart[((size_t)p * 48 + bh) * 4096 + i];
        kvfinal[(size_t)bh * 4096 + i] = s;
    } else if (t < 64) {
        float s = 0.f;
        #pragma unroll
        for (int p = 0; p < NSPLIT; p++) s += kspart[((size_t)p * 48 + bh) * 64 + t];
        ksfinal[bh * 64 + t] = s;
    }
}

// ---------- out_pre = (q @ kv) / (q . ksum + 1e-6), bf16 ----------
__global__ __launch_bounds__(256) void attn_apply(const ushort* __restrict__ qbuf,
                                                  const float* __restrict__ kvfinal,
                                                  const float* __restrict__ ksfinal,
                                                  ushort* __restrict__ outpre) {
    __shared__ ushort kvb[64 * 80];
    const int bh = blockIdx.y, b = bh / NH, h = bh % NH;
    const int t = threadIdx.x, w = t >> 6, lane = t & 63, l16 = lane & 15, quad = lane >> 4;

    for (int i = t; i < 4096; i += 256) {
        const int d = i >> 6, e = i & 63;
        kvb[d * 80 + e] = f2bf(kvfinal[(size_t)bh * 4096 + i]);
    }
    for (int i = t; i < 1024; i += 256) {
        const int d = i >> 4, c = i & 15;
        kvb[d * 80 + 64 + c] = (c == 0) ? f2bf(ksfinal[bh * 64 + d]) : (ushort)0;
    }
    __syncthreads();

    short8 bfr[5][2];
    #pragma unroll
    for (int et = 0; et < 5; et++)
        #pragma unroll
        for (int ks = 0; ks < 2; ks++) {
            short8 v;
            #pragma unroll
            for (int j = 0; j < 8; j++)
                v[j] = (short)kvb[(ks * 32 + quad * 8 + j) * 80 + et * 16 + l16];
            bfr[et][ks] = v;
        }

    const ushort* qbase = qbuf + (size_t)(b * NN) * NC + h * ND;
    ushort* obase = outpre + (size_t)(b * NN) * NC + h * ND;
    const int n0 = blockIdx.x * 512;

    for (int it = 0; it < 8; it++) {
        const int nt = n0 + (it * 4 + w) * 16;
        const ushort* qp = qbase + (size_t)(nt + l16) * NC + quad * 8;
        const short8 a0 = *(const short8*)qp;
        const short8 a1 = *(const short8*)(qp + 32);
        floatx4 acc[5] = {};
        #pragma unroll
        for (int et = 0; et < 5; et++) {
            acc[et] = __builtin_amdgcn_mfma_f32_16x16x32_bf16(a0, bfr[et][0], acc[et], 0, 0, 0);
            acc[et] = __builtin_amdgcn_mfma_f32_16x16x32_bf16(a1, bfr[et][1], acc[et], 0, 0, 0);
        }
        float dv[4];
        #pragma unroll
        for (int r = 0; r < 4; r++) dv[r] = __shfl(acc[4][r], lane & 48);
        #pragma unroll
        for (int et = 0; et < 4; et++)
            #pragma unroll
            for (int r = 0; r < 4; r++) {
                const float o = acc[et][r] / (dv[r] + 1e-6f);
                obase[(size_t)(nt + quad * 4 + r) * NC + et * 16 + l16] = f2bf(o);
            }
    }
}

extern "C" void kernel_launch(void* const* d_in, const int* in_sizes, int n_in,
                              void* d_out, int out_size, void* d_ws, size_t ws_size,
                              hipStream_t stream) {
    (void)in_sizes; (void)n_in; (void)out_size; (void)ws_size;
    const float* X     = (const float*)d_in[0];
    const float* Wqkv  = (const float*)d_in[1];
    const float* Wproj = (const float*)d_in[2];
    const float* bproj = (const float*)d_in[3];
    float* out = (float*)d_out;

    char* ws = (char*)d_ws;
    size_t off = 0;
    ushort* qbuf    = (ushort*)(ws + off); off += (size_t)MTOT * NC * 2;
    ushort* kT      = (ushort*)(ws + off); off += (size_t)NC * MTOT * 2;
    ushort* vT      = (ushort*)(ws + off); off += (size_t)NC * MTOT * 2;
    ushort* outpre  = (ushort*)(ws + off); off += (size_t)MTOT * NC * 2;
    ushort* xbf     = (ushort*)(ws + off); off += (size_t)MTOT * NC * 2;
    ushort* wqkvbf  = (ushort*)(ws + off); off += (size_t)3 * NC * NC * 2;
    ushort* wprojbf = (ushort*)(ws + off); off += (size_t)NC * NC * 2;
    float* kvpart  = (float*)xbf;                 // aliases xbf (dead after qkv GEMM)
    float* kspart  = kvpart + (size_t)NSPLIT * 48 * 4096;
    float* kvfinal = kspart + (size_t)NSPLIT * 48 * 64;
    float* ksfinal = kvfinal + (size_t)48 * 4096;

    const int ncvt = (MTOT * NC + 3 * NC * NC + NC * NC) / 8 / 256;
    cvt_all<<<ncvt, 256, 0, stream>>>(X, Wqkv, Wproj, xbf, wqkvbf, wprojbf);

    gemm_qkv<<<4608, 256, 0, stream>>>(xbf, wqkvbf, qbuf, kT, vT);
    kv_ksum<<<dim3(NSPLIT, 48), 256, 0, stream>>>(kT, vT, kvpart, kspart);
    reduce_kvks<<<dim3(17, 48), 256, 0, stream>>>(kvpart, kspart, kvfinal, ksfinal);
    attn_apply<<<dim3(NSPLIT, 48), 256, 0, stream>>>(qbuf, kvfinal, ksfinal, outpre);
    gemm_proj<<<1536, 256, 0, stream>>>(outpre, wprojbf, bproj, out);
}